// Round 4
// baseline (126.494 us; speedup 1.0000x reference)
//
#include <hip/hip_runtime.h>

// MLP3D fused, MI355X gfx950 — round 4 (= round-3 design, compile fix).
// vs r2: (a) M_PB=64 -> LDS 34.8KB -> 4 blocks/CU (was 2) for cross-block
// overlap of epilogues/barriers with MFMA; (b) part-branch GEMM folded into
// L1 by reordering the k-loop per wave (masked kb pair first, head computed
// from an accumulator snapshot) -- saves 20% of all MFMA; (c) bias loaded
// into acc init; (d) cvt_pkrtz packed f16 epilogues (fixed: builtin returns
// __fp16 ext-vector, not _Float16); (e) lookahead-1 A prefetch, lb(256,4).

#define NPTS 131072
#define M_PB 64
#define AST 264   // activation row stride in halves (256+8)

typedef _Float16 half8   __attribute__((ext_vector_type(8)));
typedef _Float16 half4_t __attribute__((ext_vector_type(4)));
typedef __fp16   fp16x2  __attribute__((ext_vector_type(2)));
typedef float    float4_t __attribute__((ext_vector_type(4)));

// ---- fused prep: W0/W1/W2 (f32 [K][256]) -> f16 MFMA-fragment-major ----
// dst[((tile*KB + kb)*64 + lane)*8 + j] = W[(kb*32 + (lane>>4)*8 + j)*256 + tile*16 + (lane&15)]
__global__ void prep(const float* __restrict__ W0, const float* __restrict__ W1,
                     const float* __restrict__ W2, _Float16* __restrict__ ws) {
  int id = blockIdx.x * 256 + threadIdx.x;   // 147456 total
  _Float16 v;
  if (id < 16384) {            // W0sw: 16 tiles x 2 kb x 512
    int e = id, j = e & 7, l = (e >> 3) & 63, kb = (e >> 9) & 1, tt = e >> 10;
    int c = l & 15, q = l >> 4;
    int k = kb * 32 + q * 8 + j, n = tt * 16 + c;
    v = (k < 63) ? (_Float16)W0[k * 256 + n] : (_Float16)0.f;
  } else if (id < 81920) {     // W1sw: 16 x 8 x 512
    int e = id - 16384, j = e & 7, l = (e >> 3) & 63, kb = (e >> 9) & 7, tt = e >> 12;
    int c = l & 15, q = l >> 4;
    int k = kb * 32 + q * 8 + j, n = tt * 16 + c;
    v = (_Float16)W1[k * 256 + n];
  } else {                     // W2sw
    int e = id - 81920, j = e & 7, l = (e >> 3) & 63, kb = (e >> 9) & 7, tt = e >> 12;
    int c = l & 15, q = l >> 4;
    int k = kb * 32 + q * 8 + j, n = tt * 16 + c;
    v = (_Float16)W2[k * 256 + n];
  }
  ws[id] = v;
}

__device__ __forceinline__ half4_t pack4(float a, float b, float cc, float d) {
  fp16x2 p0 = __builtin_amdgcn_cvt_pkrtz(a, b);
  fp16x2 p1 = __builtin_amdgcn_cvt_pkrtz(cc, d);
  half4_t h;
  h[0] = (_Float16)p0[0]; h[1] = (_Float16)p0[1];
  h[2] = (_Float16)p1[0]; h[3] = (_Float16)p1[1];
  return h;
}

__global__ __launch_bounds__(256, 4) void mlp_main(
    const float* __restrict__ coords,
    const _Float16* __restrict__ W0sw,  // [16 tiles][2 kb][64 lane][8]
    const _Float16* __restrict__ W1sw,  // [16 tiles][8 kb][64 lane][8]
    const _Float16* __restrict__ W2sw,
    const float* __restrict__ b0, const float* __restrict__ b1,
    const float* __restrict__ b2,
    const float* __restrict__ Wocc, const float* __restrict__ bocc,
    const float* __restrict__ Wc, const float* __restrict__ bc,
    float* __restrict__ out) {
  __shared__ _Float16 actX[M_PB * AST];   // E -> h -> t1 (one buffer, barriered)
  __shared__ float occ_s[4][M_PB];

  const int t = threadIdx.x;
  const int w = t >> 6;          // wave = out-neuron slice [64w,64w+64) = part id
  const int l = t & 63;
  const int c = l & 15;
  const int q = l >> 4;
  const int m0 = blockIdx.x * M_PB;

  // ---- positional encoding: wave w computes k in [16w,16w+16) for all 64 pts,
  //      lane = point ----
  {
    const float* cp = coords + (size_t)(m0 + l) * 3;
    float x0 = cp[0], x1 = cp[1], x2 = cp[2];
    float v[16];
#pragma unroll
    for (int u = 0; u < 16; ++u) {
      int k = 16 * w + u;   // wave-uniform
      float r;
      if (k >= 63) r = 0.f;
      else if (k < 3) r = (k == 0) ? x0 : (k == 1 ? x1 : x2);
      else {
        int kk = k - 3;
        int f = kk / 6;
        int rem = kk - 6 * f;
        int s = (rem >= 3) ? 1 : 0;
        int i3 = rem - 3 * s;
        float xi = (i3 == 0) ? x0 : (i3 == 1 ? x1 : x2);
        float arg = xi * (float)(1 << f);
        float nn = rintf(arg * 0.15915494309189535f);
        float rr = fmaf(nn, -6.28318548202514648f, arg);
        rr = fmaf(nn, 1.7484555e-7f, rr);
        r = s ? __cosf(rr) : __sinf(rr);
      }
      v[u] = r;
    }
    half8 e0, e1;
#pragma unroll
    for (int u = 0; u < 4; ++u) {
      fp16x2 p = __builtin_amdgcn_cvt_pkrtz(v[2 * u], v[2 * u + 1]);
      e0[2 * u] = (_Float16)p[0]; e0[2 * u + 1] = (_Float16)p[1];
      fp16x2 p2 = __builtin_amdgcn_cvt_pkrtz(v[8 + 2 * u], v[9 + 2 * u]);
      e1[2 * u] = (_Float16)p2[0]; e1[2 * u + 1] = (_Float16)p2[1];
    }
    *(half8*)&actX[l * AST + 16 * w] = e0;
    *(half8*)&actX[l * AST + 16 * w + 8] = e1;
  }
  __syncthreads();                                   // (1) E ready

  float4_t acc[4][4];
  const _Float16* ap = actX + c * AST + q * 8;

  // ---- layer 0: h = E @ W0 + b0 (no relu), K=64 ----
  {
    const _Float16* wb = W0sw + (size_t)(w * 4) * 1024 + l * 8;  // tile stride 2*512
    half8 a0[4], a1[4];
#pragma unroll
    for (int tn = 0; tn < 4; ++tn) {
      a0[tn] = *(const half8*)(wb + tn * 1024);
      a1[tn] = *(const half8*)(wb + tn * 1024 + 512);
    }
#pragma unroll
    for (int tn = 0; tn < 4; ++tn) {
      float4_t bz = *(const float4_t*)(b0 + 64 * w + tn * 16 + q * 4);
#pragma unroll
      for (int tm = 0; tm < 4; ++tm) acc[tn][tm] = bz;
    }
#pragma unroll
    for (int kb = 0; kb < 2; ++kb) {
      half8 b[4];
#pragma unroll
      for (int tm = 0; tm < 4; ++tm) b[tm] = *(const half8*)(ap + tm * 16 * AST + kb * 32);
#pragma unroll
      for (int tn = 0; tn < 4; ++tn)
#pragma unroll
        for (int tm = 0; tm < 4; ++tm)
          acc[tn][tm] = __builtin_amdgcn_mfma_f32_16x16x32_f16(
              kb ? a1[tn] : a0[tn], b[tm], acc[tn][tm], 0, 0, 0);
    }
  }
  __syncthreads();                                   // (2) all E reads done
#pragma unroll
  for (int tn = 0; tn < 4; ++tn)
#pragma unroll
    for (int tm = 0; tm < 4; ++tm) {
      float4_t v = acc[tn][tm];
      *(half4_t*)&actX[(tm * 16 + c) * AST + 64 * w + tn * 16 + q * 4] =
          pack4(v[0], v[1], v[2], v[3]);
    }
  __syncthreads();                                   // (3) h ready

  // ---- layer 1 (+ part head folded in): masked kb pair FIRST, snapshot ----
  {
    const _Float16* wb = W1sw + (size_t)(w * 4) * 4096 + l * 8;  // tile stride 8*512
    const int w2 = 2 * w;
    float bcw = bc[w];
#pragma unroll
    for (int tn = 0; tn < 4; ++tn) {
      float4_t bz = *(const float4_t*)(b1 + 64 * w + tn * 16 + q * 4);
#pragma unroll
      for (int tm = 0; tm < 4; ++tm) acc[tn][tm] = bz;
    }
    auto kbof = [&](int j) {
      return (j < 2) ? (w2 + j) : ((j - 2) + ((j - 2) >= w2 ? 2 : 0));
    };
    half8 a[4], an[4];
#pragma unroll
    for (int tn = 0; tn < 4; ++tn) a[tn] = *(const half8*)(wb + tn * 4096 + kbof(0) * 512);
#pragma unroll
    for (int j = 0; j < 8; ++j) {
      const int kb = kbof(j);
      half8 b[4];
#pragma unroll
      for (int tm = 0; tm < 4; ++tm) b[tm] = *(const half8*)(ap + tm * 16 * AST + kb * 32);
      if (j + 1 < 8) {
        const int kbn = kbof(j + 1);
#pragma unroll
        for (int tn = 0; tn < 4; ++tn) an[tn] = *(const half8*)(wb + tn * 4096 + kbn * 512);
      }
#pragma unroll
      for (int tn = 0; tn < 4; ++tn)
#pragma unroll
        for (int tm = 0; tm < 4; ++tm)
          acc[tn][tm] = __builtin_amdgcn_mfma_f32_16x16x32_f16(a[tn], b[tm], acc[tn][tm], 0, 0, 0);
      if (j == 1) {
        // snapshot: acc = b1 + (x*mask_w) @ W1-slice  -> class head for part w
        float pcls[4] = {0.f, 0.f, 0.f, 0.f};
#pragma unroll
        for (int tn = 0; tn < 4; ++tn) {
          float4_t wcv = *(const float4_t*)(Wc + 256 * w + 64 * w + tn * 16 + q * 4);
#pragma unroll
          for (int tm = 0; tm < 4; ++tm) {
            float4_t v = acc[tn][tm];
#pragma unroll
            for (int r = 0; r < 4; ++r) pcls[tm] += fmaxf(v[r], 0.f) * wcv[r];
          }
        }
#pragma unroll
        for (int tm = 0; tm < 4; ++tm) {
          float s = pcls[tm];
          s += __shfl_xor(s, 16, 64);
          s += __shfl_xor(s, 32, 64);
          if (l < 16)
            out[(size_t)NPTS + (size_t)(m0 + tm * 16 + c) * 4 + w] = s + bcw;
        }
      }
      if (j + 1 < 8) {
#pragma unroll
        for (int tn = 0; tn < 4; ++tn) a[tn] = an[tn];
      }
    }
  }
  __syncthreads();                                   // (4) all h reads done
#pragma unroll
  for (int tn = 0; tn < 4; ++tn)
#pragma unroll
    for (int tm = 0; tm < 4; ++tm) {
      float4_t v = acc[tn][tm];
      *(half4_t*)&actX[(tm * 16 + c) * AST + 64 * w + tn * 16 + q * 4] =
          pack4(fmaxf(v[0], 0.f), fmaxf(v[1], 0.f), fmaxf(v[2], 0.f), fmaxf(v[3], 0.f));
    }
  __syncthreads();                                   // (5) t1 ready

  // ---- layer 2 + occ head (t2 never materialized) ----
  {
    const _Float16* wb = W2sw + (size_t)(w * 4) * 4096 + l * 8;
#pragma unroll
    for (int tn = 0; tn < 4; ++tn) {
      float4_t bz = *(const float4_t*)(b2 + 64 * w + tn * 16 + q * 4);
#pragma unroll
      for (int tm = 0; tm < 4; ++tm) acc[tn][tm] = bz;
    }
    half8 a[4], an[4];
#pragma unroll
    for (int tn = 0; tn < 4; ++tn) a[tn] = *(const half8*)(wb + tn * 4096);
#pragma unroll
    for (int kb = 0; kb < 8; ++kb) {
      half8 b[4];
#pragma unroll
      for (int tm = 0; tm < 4; ++tm) b[tm] = *(const half8*)(ap + tm * 16 * AST + kb * 32);
      if (kb + 1 < 8) {
#pragma unroll
        for (int tn = 0; tn < 4; ++tn)
          an[tn] = *(const half8*)(wb + tn * 4096 + (kb + 1) * 512);
      }
#pragma unroll
      for (int tn = 0; tn < 4; ++tn)
#pragma unroll
        for (int tm = 0; tm < 4; ++tm)
          acc[tn][tm] = __builtin_amdgcn_mfma_f32_16x16x32_f16(a[tn], b[tm], acc[tn][tm], 0, 0, 0);
      if (kb + 1 < 8) {
#pragma unroll
        for (int tn = 0; tn < 4; ++tn) a[tn] = an[tn];
      }
    }
    float pocc[4] = {0.f, 0.f, 0.f, 0.f};
#pragma unroll
    for (int tn = 0; tn < 4; ++tn) {
      float4_t wov = *(const float4_t*)(Wocc + 64 * w + tn * 16 + q * 4);
#pragma unroll
      for (int tm = 0; tm < 4; ++tm) {
        float4_t v = acc[tn][tm];
#pragma unroll
        for (int r = 0; r < 4; ++r) pocc[tm] += fmaxf(v[r], 0.f) * wov[r];
      }
    }
#pragma unroll
    for (int tm = 0; tm < 4; ++tm) {
      float s = pocc[tm];
      s += __shfl_xor(s, 16, 64);
      s += __shfl_xor(s, 32, 64);
      if (l < 16) occ_s[w][tm * 16 + c] = s;
    }
  }
  __syncthreads();                                   // (6) occ partials ready
  if (t < M_PB) {
    out[m0 + t] = occ_s[0][t] + occ_s[1][t] + occ_s[2][t] + occ_s[3][t] + bocc[0];
  }
}

extern "C" void kernel_launch(void* const* d_in, const int* in_sizes, int n_in,
                              void* d_out, int out_size, void* d_ws, size_t ws_size,
                              hipStream_t stream) {
  const float* coords = (const float*)d_in[0];
  const float* W0   = (const float*)d_in[1];
  const float* b0   = (const float*)d_in[2];
  const float* W1   = (const float*)d_in[3];
  const float* b1   = (const float*)d_in[4];
  const float* W2   = (const float*)d_in[5];
  const float* b2   = (const float*)d_in[6];
  const float* Wocc = (const float*)d_in[7];
  const float* bocc = (const float*)d_in[8];
  const float* Wc   = (const float*)d_in[9];
  const float* bc   = (const float*)d_in[10];
  float* out = (float*)d_out;

  _Float16* ws = (_Float16*)d_ws;       // W0sw[16384] | W1sw[65536] | W2sw[65536]
  _Float16* W0sw = ws;
  _Float16* W1sw = ws + 16384;
  _Float16* W2sw = ws + 81920;

  prep<<<576, 256, 0, stream>>>(W0, W1, W2, ws);
  mlp_main<<<NPTS / M_PB, 256, 0, stream>>>(coords, W0sw, W1sw, W2sw,
                                            b0, b1, b2, Wocc, bocc, Wc, bc, out);
}

// Round 5
// 121.867 us; speedup vs baseline: 1.0380x; 1.0380x over previous
//
#include <hip/hip_runtime.h>

// MLP3D fused, MI355X gfx950 — round 5.
// = round-4 design with ONE change: __launch_bounds__(256,3) instead of (256,4).
// r4's (256,4) capped regs at 128 total (64 arch + 64 acc) -> ~25 regs/thread
// spilled to scratch (WRITE_SIZE 6.6->53.7 MB, MfmaUtil 30->22%). (256,3)
// gives ~170 regs: mandatory live set (~130) fits, 3 blocks/CU via VGPR,
// LDS (34.8KB) would allow 4. 12 waves/CU vs r2's 8.

#define NPTS 131072
#define M_PB 64
#define AST 264   // activation row stride in halves (256+8)

typedef _Float16 half8   __attribute__((ext_vector_type(8)));
typedef _Float16 half4_t __attribute__((ext_vector_type(4)));
typedef __fp16   fp16x2  __attribute__((ext_vector_type(2)));
typedef float    float4_t __attribute__((ext_vector_type(4)));

// ---- fused prep: W0/W1/W2 (f32 [K][256]) -> f16 MFMA-fragment-major ----
// dst[((tile*KB + kb)*64 + lane)*8 + j] = W[(kb*32 + (lane>>4)*8 + j)*256 + tile*16 + (lane&15)]
__global__ void prep(const float* __restrict__ W0, const float* __restrict__ W1,
                     const float* __restrict__ W2, _Float16* __restrict__ ws) {
  int id = blockIdx.x * 256 + threadIdx.x;   // 147456 total
  _Float16 v;
  if (id < 16384) {            // W0sw: 16 tiles x 2 kb x 512
    int e = id, j = e & 7, l = (e >> 3) & 63, kb = (e >> 9) & 1, tt = e >> 10;
    int c = l & 15, q = l >> 4;
    int k = kb * 32 + q * 8 + j, n = tt * 16 + c;
    v = (k < 63) ? (_Float16)W0[k * 256 + n] : (_Float16)0.f;
  } else if (id < 81920) {     // W1sw: 16 x 8 x 512
    int e = id - 16384, j = e & 7, l = (e >> 3) & 63, kb = (e >> 9) & 7, tt = e >> 12;
    int c = l & 15, q = l >> 4;
    int k = kb * 32 + q * 8 + j, n = tt * 16 + c;
    v = (_Float16)W1[k * 256 + n];
  } else {                     // W2sw
    int e = id - 81920, j = e & 7, l = (e >> 3) & 63, kb = (e >> 9) & 7, tt = e >> 12;
    int c = l & 15, q = l >> 4;
    int k = kb * 32 + q * 8 + j, n = tt * 16 + c;
    v = (_Float16)W2[k * 256 + n];
  }
  ws[id] = v;
}

__device__ __forceinline__ half4_t pack4(float a, float b, float cc, float d) {
  fp16x2 p0 = __builtin_amdgcn_cvt_pkrtz(a, b);
  fp16x2 p1 = __builtin_amdgcn_cvt_pkrtz(cc, d);
  half4_t h;
  h[0] = (_Float16)p0[0]; h[1] = (_Float16)p0[1];
  h[2] = (_Float16)p1[0]; h[3] = (_Float16)p1[1];
  return h;
}

__global__ __launch_bounds__(256, 3) void mlp_main(
    const float* __restrict__ coords,
    const _Float16* __restrict__ W0sw,  // [16 tiles][2 kb][64 lane][8]
    const _Float16* __restrict__ W1sw,  // [16 tiles][8 kb][64 lane][8]
    const _Float16* __restrict__ W2sw,
    const float* __restrict__ b0, const float* __restrict__ b1,
    const float* __restrict__ b2,
    const float* __restrict__ Wocc, const float* __restrict__ bocc,
    const float* __restrict__ Wc, const float* __restrict__ bc,
    float* __restrict__ out) {
  __shared__ _Float16 actX[M_PB * AST];   // E -> h -> t1 (one buffer, barriered)
  __shared__ float occ_s[4][M_PB];

  const int t = threadIdx.x;
  const int w = t >> 6;          // wave = out-neuron slice [64w,64w+64) = part id
  const int l = t & 63;
  const int c = l & 15;
  const int q = l >> 4;
  const int m0 = blockIdx.x * M_PB;

  // ---- positional encoding: wave w computes k in [16w,16w+16) for all 64 pts,
  //      lane = point ----
  {
    const float* cp = coords + (size_t)(m0 + l) * 3;
    float x0 = cp[0], x1 = cp[1], x2 = cp[2];
    float v[16];
#pragma unroll
    for (int u = 0; u < 16; ++u) {
      int k = 16 * w + u;   // wave-uniform
      float r;
      if (k >= 63) r = 0.f;
      else if (k < 3) r = (k == 0) ? x0 : (k == 1 ? x1 : x2);
      else {
        int kk = k - 3;
        int f = kk / 6;
        int rem = kk - 6 * f;
        int s = (rem >= 3) ? 1 : 0;
        int i3 = rem - 3 * s;
        float xi = (i3 == 0) ? x0 : (i3 == 1 ? x1 : x2);
        float arg = xi * (float)(1 << f);
        float nn = rintf(arg * 0.15915494309189535f);
        float rr = fmaf(nn, -6.28318548202514648f, arg);
        rr = fmaf(nn, 1.7484555e-7f, rr);
        r = s ? __cosf(rr) : __sinf(rr);
      }
      v[u] = r;
    }
    half8 e0, e1;
#pragma unroll
    for (int u = 0; u < 4; ++u) {
      fp16x2 p = __builtin_amdgcn_cvt_pkrtz(v[2 * u], v[2 * u + 1]);
      e0[2 * u] = (_Float16)p[0]; e0[2 * u + 1] = (_Float16)p[1];
      fp16x2 p2 = __builtin_amdgcn_cvt_pkrtz(v[8 + 2 * u], v[9 + 2 * u]);
      e1[2 * u] = (_Float16)p2[0]; e1[2 * u + 1] = (_Float16)p2[1];
    }
    *(half8*)&actX[l * AST + 16 * w] = e0;
    *(half8*)&actX[l * AST + 16 * w + 8] = e1;
  }
  __syncthreads();                                   // (1) E ready

  float4_t acc[4][4];
  const _Float16* ap = actX + c * AST + q * 8;

  // ---- layer 0: h = E @ W0 + b0 (no relu), K=64 ----
  {
    const _Float16* wb = W0sw + (size_t)(w * 4) * 1024 + l * 8;  // tile stride 2*512
    half8 a0[4], a1[4];
#pragma unroll
    for (int tn = 0; tn < 4; ++tn) {
      a0[tn] = *(const half8*)(wb + tn * 1024);
      a1[tn] = *(const half8*)(wb + tn * 1024 + 512);
    }
#pragma unroll
    for (int tn = 0; tn < 4; ++tn) {
      float4_t bz = *(const float4_t*)(b0 + 64 * w + tn * 16 + q * 4);
#pragma unroll
      for (int tm = 0; tm < 4; ++tm) acc[tn][tm] = bz;
    }
#pragma unroll
    for (int kb = 0; kb < 2; ++kb) {
      half8 b[4];
#pragma unroll
      for (int tm = 0; tm < 4; ++tm) b[tm] = *(const half8*)(ap + tm * 16 * AST + kb * 32);
#pragma unroll
      for (int tn = 0; tn < 4; ++tn)
#pragma unroll
        for (int tm = 0; tm < 4; ++tm)
          acc[tn][tm] = __builtin_amdgcn_mfma_f32_16x16x32_f16(
              kb ? a1[tn] : a0[tn], b[tm], acc[tn][tm], 0, 0, 0);
    }
  }
  __syncthreads();                                   // (2) all E reads done
#pragma unroll
  for (int tn = 0; tn < 4; ++tn)
#pragma unroll
    for (int tm = 0; tm < 4; ++tm) {
      float4_t v = acc[tn][tm];
      *(half4_t*)&actX[(tm * 16 + c) * AST + 64 * w + tn * 16 + q * 4] =
          pack4(v[0], v[1], v[2], v[3]);
    }
  __syncthreads();                                   // (3) h ready

  // ---- layer 1 (+ part head folded in): masked kb pair FIRST, snapshot ----
  {
    const _Float16* wb = W1sw + (size_t)(w * 4) * 4096 + l * 8;  // tile stride 8*512
    const int w2 = 2 * w;
    float bcw = bc[w];
#pragma unroll
    for (int tn = 0; tn < 4; ++tn) {
      float4_t bz = *(const float4_t*)(b1 + 64 * w + tn * 16 + q * 4);
#pragma unroll
      for (int tm = 0; tm < 4; ++tm) acc[tn][tm] = bz;
    }
    auto kbof = [&](int j) {
      return (j < 2) ? (w2 + j) : ((j - 2) + ((j - 2) >= w2 ? 2 : 0));
    };
    half8 a[4], an[4];
#pragma unroll
    for (int tn = 0; tn < 4; ++tn) a[tn] = *(const half8*)(wb + tn * 4096 + kbof(0) * 512);
#pragma unroll
    for (int j = 0; j < 8; ++j) {
      const int kb = kbof(j);
      half8 b[4];
#pragma unroll
      for (int tm = 0; tm < 4; ++tm) b[tm] = *(const half8*)(ap + tm * 16 * AST + kb * 32);
      if (j + 1 < 8) {
        const int kbn = kbof(j + 1);
#pragma unroll
        for (int tn = 0; tn < 4; ++tn) an[tn] = *(const half8*)(wb + tn * 4096 + kbn * 512);
      }
#pragma unroll
      for (int tn = 0; tn < 4; ++tn)
#pragma unroll
        for (int tm = 0; tm < 4; ++tm)
          acc[tn][tm] = __builtin_amdgcn_mfma_f32_16x16x32_f16(a[tn], b[tm], acc[tn][tm], 0, 0, 0);
      if (j == 1) {
        // snapshot: acc = b1 + (x*mask_w) @ W1-slice  -> class head for part w
        float pcls[4] = {0.f, 0.f, 0.f, 0.f};
#pragma unroll
        for (int tn = 0; tn < 4; ++tn) {
          float4_t wcv = *(const float4_t*)(Wc + 256 * w + 64 * w + tn * 16 + q * 4);
#pragma unroll
          for (int tm = 0; tm < 4; ++tm) {
            float4_t v = acc[tn][tm];
#pragma unroll
            for (int r = 0; r < 4; ++r) pcls[tm] += fmaxf(v[r], 0.f) * wcv[r];
          }
        }
#pragma unroll
        for (int tm = 0; tm < 4; ++tm) {
          float s = pcls[tm];
          s += __shfl_xor(s, 16, 64);
          s += __shfl_xor(s, 32, 64);
          if (l < 16)
            out[(size_t)NPTS + (size_t)(m0 + tm * 16 + c) * 4 + w] = s + bcw;
        }
      }
      if (j + 1 < 8) {
#pragma unroll
        for (int tn = 0; tn < 4; ++tn) a[tn] = an[tn];
      }
    }
  }
  __syncthreads();                                   // (4) all h reads done
#pragma unroll
  for (int tn = 0; tn < 4; ++tn)
#pragma unroll
    for (int tm = 0; tm < 4; ++tm) {
      float4_t v = acc[tn][tm];
      *(half4_t*)&actX[(tm * 16 + c) * AST + 64 * w + tn * 16 + q * 4] =
          pack4(fmaxf(v[0], 0.f), fmaxf(v[1], 0.f), fmaxf(v[2], 0.f), fmaxf(v[3], 0.f));
    }
  __syncthreads();                                   // (5) t1 ready

  // ---- layer 2 + occ head (t2 never materialized) ----
  {
    const _Float16* wb = W2sw + (size_t)(w * 4) * 4096 + l * 8;
#pragma unroll
    for (int tn = 0; tn < 4; ++tn) {
      float4_t bz = *(const float4_t*)(b2 + 64 * w + tn * 16 + q * 4);
#pragma unroll
      for (int tm = 0; tm < 4; ++tm) acc[tn][tm] = bz;
    }
    half8 a[4], an[4];
#pragma unroll
    for (int tn = 0; tn < 4; ++tn) a[tn] = *(const half8*)(wb + tn * 4096);
#pragma unroll
    for (int kb = 0; kb < 8; ++kb) {
      half8 b[4];
#pragma unroll
      for (int tm = 0; tm < 4; ++tm) b[tm] = *(const half8*)(ap + tm * 16 * AST + kb * 32);
      if (kb + 1 < 8) {
#pragma unroll
        for (int tn = 0; tn < 4; ++tn)
          an[tn] = *(const half8*)(wb + tn * 4096 + (kb + 1) * 512);
      }
#pragma unroll
      for (int tn = 0; tn < 4; ++tn)
#pragma unroll
        for (int tm = 0; tm < 4; ++tm)
          acc[tn][tm] = __builtin_amdgcn_mfma_f32_16x16x32_f16(a[tn], b[tm], acc[tn][tm], 0, 0, 0);
      if (kb + 1 < 8) {
#pragma unroll
        for (int tn = 0; tn < 4; ++tn) a[tn] = an[tn];
      }
    }
    float pocc[4] = {0.f, 0.f, 0.f, 0.f};
#pragma unroll
    for (int tn = 0; tn < 4; ++tn) {
      float4_t wov = *(const float4_t*)(Wocc + 64 * w + tn * 16 + q * 4);
#pragma unroll
      for (int tm = 0; tm < 4; ++tm) {
        float4_t v = acc[tn][tm];
#pragma unroll
        for (int r = 0; r < 4; ++r) pocc[tm] += fmaxf(v[r], 0.f) * wov[r];
      }
    }
#pragma unroll
    for (int tm = 0; tm < 4; ++tm) {
      float s = pocc[tm];
      s += __shfl_xor(s, 16, 64);
      s += __shfl_xor(s, 32, 64);
      if (l < 16) occ_s[w][tm * 16 + c] = s;
    }
  }
  __syncthreads();                                   // (6) occ partials ready
  if (t < M_PB) {
    out[m0 + t] = occ_s[0][t] + occ_s[1][t] + occ_s[2][t] + occ_s[3][t] + bocc[0];
  }
}

extern "C" void kernel_launch(void* const* d_in, const int* in_sizes, int n_in,
                              void* d_out, int out_size, void* d_ws, size_t ws_size,
                              hipStream_t stream) {
  const float* coords = (const float*)d_in[0];
  const float* W0   = (const float*)d_in[1];
  const float* b0   = (const float*)d_in[2];
  const float* W1   = (const float*)d_in[3];
  const float* b1   = (const float*)d_in[4];
  const float* W2   = (const float*)d_in[5];
  const float* b2   = (const float*)d_in[6];
  const float* Wocc = (const float*)d_in[7];
  const float* bocc = (const float*)d_in[8];
  const float* Wc   = (const float*)d_in[9];
  const float* bc   = (const float*)d_in[10];
  float* out = (float*)d_out;

  _Float16* ws = (_Float16*)d_ws;       // W0sw[16384] | W1sw[65536] | W2sw[65536]
  _Float16* W0sw = ws;
  _Float16* W1sw = ws + 16384;
  _Float16* W2sw = ws + 81920;

  prep<<<576, 256, 0, stream>>>(W0, W1, W2, ws);
  mlp_main<<<NPTS / M_PB, 256, 0, stream>>>(coords, W0sw, W1sw, W2sw,
                                            b0, b1, b2, Wocc, bocc, Wc, bc, out);
}

// Round 7
// 115.618 us; speedup vs baseline: 1.0941x; 1.0541x over previous
//
#include <hip/hip_runtime.h>

// MLP3D fused, MI355X gfx950 — round 7 (= r6 with the layer-1 pipeline bug fixed).
// r6 bug: layer-1 prefetched into A[j%3] BEFORE the MFMA consumed it (3-buffer
// rotation with lookahead-3 targets the in-use buffer — prefetch must follow
// the MFMA in program order, as layer 2 already did). Occ was corrupted via t1.
// Design: M_PB=128, per-wave-contiguous weight layout [slice][kb][tn][lane][8],
// 3-buffer A-prefetch, part-head folded into L1, bias-in-acc, pkrtz epilogues.

#define NPTS 131072
#define M_PB 128
#define AST 264   // activation row stride in halves (256+8)

typedef _Float16 half8   __attribute__((ext_vector_type(8)));
typedef _Float16 half4_t __attribute__((ext_vector_type(4)));
typedef __fp16   fp16x2  __attribute__((ext_vector_type(2)));
typedef float    float4_t __attribute__((ext_vector_type(4)));

// ---- prep: W (f32 [K][256]) -> f16 per-wave-contiguous fragment layout ----
// dst[(((s*KB + kb)*4 + tn)*64 + l)*8 + j] = W[(kb*32 + (l>>4)*8 + j)*256 + s*64 + tn*16 + (l&15)]
__global__ void prep(const float* __restrict__ W0, const float* __restrict__ W1,
                     const float* __restrict__ W2, _Float16* __restrict__ ws) {
  int id = blockIdx.x * 256 + threadIdx.x;   // 147456 total
  _Float16 v;
  if (id < 16384) {            // W0sw: 4 slices x 2 kb x 4 tn x 512
    int e = id, j = e & 7, l = (e >> 3) & 63, tn = (e >> 9) & 3, kb = (e >> 11) & 1, s = e >> 12;
    int k = kb * 32 + (l >> 4) * 8 + j, n = s * 64 + tn * 16 + (l & 15);
    v = (k < 63) ? (_Float16)W0[k * 256 + n] : (_Float16)0.f;
  } else if (id < 81920) {     // W1sw: 4 x 8 x 4 x 512
    int e = id - 16384, j = e & 7, l = (e >> 3) & 63, tn = (e >> 9) & 3, kb = (e >> 11) & 7, s = e >> 14;
    int k = kb * 32 + (l >> 4) * 8 + j, n = s * 64 + tn * 16 + (l & 15);
    v = (_Float16)W1[k * 256 + n];
  } else {                     // W2sw
    int e = id - 81920, j = e & 7, l = (e >> 3) & 63, tn = (e >> 9) & 3, kb = (e >> 11) & 7, s = e >> 14;
    int k = kb * 32 + (l >> 4) * 8 + j, n = s * 64 + tn * 16 + (l & 15);
    v = (_Float16)W2[k * 256 + n];
  }
  ws[id] = v;
}

__device__ __forceinline__ half4_t pack4(float a, float b, float cc, float d) {
  fp16x2 p0 = __builtin_amdgcn_cvt_pkrtz(a, b);
  fp16x2 p1 = __builtin_amdgcn_cvt_pkrtz(cc, d);
  half4_t h;
  h[0] = (_Float16)p0[0]; h[1] = (_Float16)p0[1];
  h[2] = (_Float16)p1[0]; h[3] = (_Float16)p1[1];
  return h;
}

__global__ __launch_bounds__(256, 2) void mlp_main(
    const float* __restrict__ coords,
    const _Float16* __restrict__ W0sw,
    const _Float16* __restrict__ W1sw,
    const _Float16* __restrict__ W2sw,
    const float* __restrict__ b0, const float* __restrict__ b1,
    const float* __restrict__ b2,
    const float* __restrict__ Wocc, const float* __restrict__ bocc,
    const float* __restrict__ Wc, const float* __restrict__ bc,
    float* __restrict__ out) {
  __shared__ _Float16 actX[M_PB * AST];   // E -> h -> t1 (one buffer, barriered)
  __shared__ float occ_s[4][M_PB];

  const int t = threadIdx.x;
  const int w = t >> 6;          // wave = neuron slice [64w,64w+64) = part id
  const int l = t & 63;
  const int c = l & 15;
  const int q = l >> 4;
  const int m0 = blockIdx.x * M_PB;

  // ---- positional encoding: 2 threads/point, 32 k-values each ----
  {
    int m = t & 127, kh = (t >> 7) * 32;   // kh wave-uniform
    const float* cp = coords + (size_t)(m0 + m) * 3;
    float x0 = cp[0], x1 = cp[1], x2 = cp[2];
#pragma unroll
    for (int i = 0; i < 4; ++i) {
      float v[8];
#pragma unroll
      for (int u = 0; u < 8; ++u) {
        int k = kh + i * 8 + u;
        float r;
        if (k >= 63) r = 0.f;
        else if (k < 3) r = (k == 0) ? x0 : (k == 1 ? x1 : x2);
        else {
          int kk = k - 3;
          int f = kk / 6;
          int rem = kk - 6 * f;
          int s = (rem >= 3) ? 1 : 0;
          int i3 = rem - 3 * s;
          float xi = (i3 == 0) ? x0 : (i3 == 1 ? x1 : x2);
          float arg = xi * (float)(1 << f);
          float nn = rintf(arg * 0.15915494309189535f);
          float rr = fmaf(nn, -6.28318548202514648f, arg);
          rr = fmaf(nn, 1.7484555e-7f, rr);
          r = s ? __cosf(rr) : __sinf(rr);
        }
        v[u] = r;
      }
      half8 ev;
#pragma unroll
      for (int u = 0; u < 4; ++u) {
        fp16x2 p = __builtin_amdgcn_cvt_pkrtz(v[2 * u], v[2 * u + 1]);
        ev[2 * u] = (_Float16)p[0]; ev[2 * u + 1] = (_Float16)p[1];
      }
      *(half8*)&actX[m * AST + kh + i * 8] = ev;
    }
  }
  __syncthreads();                                   // (1) E ready

  float4_t acc[4][8];
  const _Float16* ap = actX + c * AST + q * 8;

  // ---- layer 0: h = E @ W0 + b0 (no relu), K=64 (2 kb, all A upfront) ----
  {
    const _Float16* wb = W0sw + (size_t)w * 4096 + l * 8;  // slice stride 2*4*512
    half8 a0[4], a1[4];
#pragma unroll
    for (int tn = 0; tn < 4; ++tn) {
      a0[tn] = *(const half8*)(wb + tn * 512);
      a1[tn] = *(const half8*)(wb + 2048 + tn * 512);
    }
#pragma unroll
    for (int tn = 0; tn < 4; ++tn) {
      float4_t bz = *(const float4_t*)(b0 + 64 * w + tn * 16 + q * 4);
#pragma unroll
      for (int tm = 0; tm < 8; ++tm) acc[tn][tm] = bz;
    }
#pragma unroll
    for (int kb = 0; kb < 2; ++kb) {
      half8 b[8];
#pragma unroll
      for (int tm = 0; tm < 8; ++tm) b[tm] = *(const half8*)(ap + tm * 16 * AST + kb * 32);
#pragma unroll
      for (int tn = 0; tn < 4; ++tn)
#pragma unroll
        for (int tm = 0; tm < 8; ++tm)
          acc[tn][tm] = __builtin_amdgcn_mfma_f32_16x16x32_f16(
              kb ? a1[tn] : a0[tn], b[tm], acc[tn][tm], 0, 0, 0);
    }
  }
  __syncthreads();                                   // (2) all E reads done
#pragma unroll
  for (int tn = 0; tn < 4; ++tn)
#pragma unroll
    for (int tm = 0; tm < 8; ++tm) {
      float4_t v = acc[tn][tm];
      *(half4_t*)&actX[(tm * 16 + c) * AST + 64 * w + tn * 16 + q * 4] =
          pack4(v[0], v[1], v[2], v[3]);
    }
  __syncthreads();                                   // (3) h ready

  // ---- layer 1 (+ part head): masked kb pair FIRST, snapshot after j==1 ----
  {
    const _Float16* wb = W1sw + (size_t)w * 16384 + l * 8;  // slice stride 8*4*512
    const int w2 = 2 * w;
    float bcw = bc[w];
#pragma unroll
    for (int tn = 0; tn < 4; ++tn) {
      float4_t bz = *(const float4_t*)(b1 + 64 * w + tn * 16 + q * 4);
#pragma unroll
      for (int tm = 0; tm < 8; ++tm) acc[tn][tm] = bz;
    }
    auto kbof = [&](int j) {
      return (j < 2) ? (w2 + j) : ((j - 2) + ((j - 2) >= w2 ? 2 : 0));
    };
    half8 A[3][4];
#pragma unroll
    for (int p = 0; p < 3; ++p) {
      const _Float16* pa = wb + kbof(p) * 2048;
#pragma unroll
      for (int tn = 0; tn < 4; ++tn) A[p][tn] = *(const half8*)(pa + tn * 512);
    }
#pragma unroll
    for (int j = 0; j < 8; ++j) {
      const int kb = kbof(j);
      half8 b[8];
#pragma unroll
      for (int tm = 0; tm < 8; ++tm) b[tm] = *(const half8*)(ap + tm * 16 * AST + kb * 32);
      // use buffer j%3 (holds kbof(j)) -- MUST consume before the prefetch
      // below overwrites the same buffer (3-buffer rotation, lookahead 3).
#pragma unroll
      for (int tn = 0; tn < 4; ++tn)
#pragma unroll
        for (int tm = 0; tm < 8; ++tm)
          acc[tn][tm] = __builtin_amdgcn_mfma_f32_16x16x32_f16(
              A[j % 3][tn], b[tm], acc[tn][tm], 0, 0, 0);
      if (j == 1) {
        // snapshot: acc = b1 + (x*mask_w) @ W1-slice -> class head for part w
        float pcls[8] = {0.f, 0.f, 0.f, 0.f, 0.f, 0.f, 0.f, 0.f};
#pragma unroll
        for (int tn = 0; tn < 4; ++tn) {
          float4_t wcv = *(const float4_t*)(Wc + 256 * w + 64 * w + tn * 16 + q * 4);
#pragma unroll
          for (int tm = 0; tm < 8; ++tm) {
            float4_t v = acc[tn][tm];
#pragma unroll
            for (int r = 0; r < 4; ++r) pcls[tm] += fmaxf(v[r], 0.f) * wcv[r];
          }
        }
#pragma unroll
        for (int tm = 0; tm < 8; ++tm) {
          float s = pcls[tm];
          s += __shfl_xor(s, 16, 64);
          s += __shfl_xor(s, 32, 64);
          if (l < 16)
            out[(size_t)NPTS + (size_t)(m0 + tm * 16 + c) * 4 + w] = s + bcw;
        }
      }
      if (j + 3 < 8) {   // prefetch AFTER use
        const _Float16* pa = wb + kbof(j + 3) * 2048;
#pragma unroll
        for (int tn = 0; tn < 4; ++tn) A[j % 3][tn] = *(const half8*)(pa + tn * 512);
      }
    }
  }
  __syncthreads();                                   // (4) all h reads done
#pragma unroll
  for (int tn = 0; tn < 4; ++tn)
#pragma unroll
    for (int tm = 0; tm < 8; ++tm) {
      float4_t v = acc[tn][tm];
      *(half4_t*)&actX[(tm * 16 + c) * AST + 64 * w + tn * 16 + q * 4] =
          pack4(fmaxf(v[0], 0.f), fmaxf(v[1], 0.f), fmaxf(v[2], 0.f), fmaxf(v[3], 0.f));
    }
  __syncthreads();                                   // (5) t1 ready

  // ---- layer 2 + occ head ----
  {
    const _Float16* wb = W2sw + (size_t)w * 16384 + l * 8;
#pragma unroll
    for (int tn = 0; tn < 4; ++tn) {
      float4_t bz = *(const float4_t*)(b2 + 64 * w + tn * 16 + q * 4);
#pragma unroll
      for (int tm = 0; tm < 8; ++tm) acc[tn][tm] = bz;
    }
    half8 A[3][4];
#pragma unroll
    for (int p = 0; p < 3; ++p)
#pragma unroll
      for (int tn = 0; tn < 4; ++tn)
        A[p][tn] = *(const half8*)(wb + p * 2048 + tn * 512);
#pragma unroll
    for (int kb = 0; kb < 8; ++kb) {
      half8 b[8];
#pragma unroll
      for (int tm = 0; tm < 8; ++tm) b[tm] = *(const half8*)(ap + tm * 16 * AST + kb * 32);
#pragma unroll
      for (int tn = 0; tn < 4; ++tn)
#pragma unroll
        for (int tm = 0; tm < 8; ++tm)
          acc[tn][tm] = __builtin_amdgcn_mfma_f32_16x16x32_f16(
              A[kb % 3][tn], b[tm], acc[tn][tm], 0, 0, 0);
      if (kb + 3 < 8) {
#pragma unroll
        for (int tn = 0; tn < 4; ++tn)
          A[kb % 3][tn] = *(const half8*)(wb + (kb + 3) * 2048 + tn * 512);
      }
    }
    float pocc[8] = {0.f, 0.f, 0.f, 0.f, 0.f, 0.f, 0.f, 0.f};
#pragma unroll
    for (int tn = 0; tn < 4; ++tn) {
      float4_t wov = *(const float4_t*)(Wocc + 64 * w + tn * 16 + q * 4);
#pragma unroll
      for (int tm = 0; tm < 8; ++tm) {
        float4_t v = acc[tn][tm];
#pragma unroll
        for (int r = 0; r < 4; ++r) pocc[tm] += fmaxf(v[r], 0.f) * wov[r];
      }
    }
#pragma unroll
    for (int tm = 0; tm < 8; ++tm) {
      float s = pocc[tm];
      s += __shfl_xor(s, 16, 64);
      s += __shfl_xor(s, 32, 64);
      if (l < 16) occ_s[w][tm * 16 + c] = s;
    }
  }
  __syncthreads();                                   // (6) occ partials ready
  if (t < M_PB) {
    out[m0 + t] = occ_s[0][t] + occ_s[1][t] + occ_s[2][t] + occ_s[3][t] + bocc[0];
  }
}

extern "C" void kernel_launch(void* const* d_in, const int* in_sizes, int n_in,
                              void* d_out, int out_size, void* d_ws, size_t ws_size,
                              hipStream_t stream) {
  const float* coords = (const float*)d_in[0];
  const float* W0   = (const float*)d_in[1];
  const float* b0   = (const float*)d_in[2];
  const float* W1   = (const float*)d_in[3];
  const float* b1   = (const float*)d_in[4];
  const float* W2   = (const float*)d_in[5];
  const float* b2   = (const float*)d_in[6];
  const float* Wocc = (const float*)d_in[7];
  const float* bocc = (const float*)d_in[8];
  const float* Wc   = (const float*)d_in[9];
  const float* bc   = (const float*)d_in[10];
  float* out = (float*)d_out;

  _Float16* ws = (_Float16*)d_ws;       // W0sw[16384] | W1sw[65536] | W2sw[65536]
  _Float16* W0sw = ws;
  _Float16* W1sw = ws + 16384;
  _Float16* W2sw = ws + 81920;

  prep<<<576, 256, 0, stream>>>(W0, W1, W2, ws);
  mlp_main<<<NPTS / M_PB, 256, 0, stream>>>(coords, W0sw, W1sw, W2sw,
                                            b0, b1, b2, Wocc, bocc, Wc, bc, out);
}